// Round 1
// baseline (2030.570 us; speedup 1.0000x reference)
//
#include <hip/hip_runtime.h>

#define DM 1024
#define NHEADS 16
#define DK 64
#define BSZ 2
#define NSEQ 8192
#define MROWS (BSZ*NSEQ)
#define CHUNK 1024

constexpr float EPS_F = 1e-6f;

// C[M x N] = A[M x K] @ W[N x K]^T + bias[N], optional feature map elu(x)+1.
// BM=BN=128, BK=16, 256 threads, 8x8 micro-tile per thread. Pure fp32 (no
// fp32 MFMA on CDNA4) -- round-1 correctness baseline.
template<int ACT>
__global__ __launch_bounds__(256, 2)
void gemm_bias_kernel(const float* __restrict__ A, const float* __restrict__ W,
                      const float* __restrict__ bias, float* __restrict__ C) {
  constexpr int BM = 128, BN = 128, BK = 16;
  constexpr int K = DM, N = DM;
  __shared__ float As[BK][BM + 4];
  __shared__ float Ws[BK][BN + 4];
  const int tid = threadIdx.x;
  const int tx = tid & 15;   // column group 0..15
  const int ty = tid >> 4;   // row group 0..15
  const int lrow = tid >> 1;        // 0..127: one tile row per 2 threads
  const int lq = (tid & 1) * 2;     // float4 quad base (0 or 2)
  const long rowA = (long)blockIdx.y * BM;
  const long colW = (long)blockIdx.x * BN;
  const float* Aptr = A + (rowA + lrow) * (long)K;
  const float* Wptr = W + (colW + lrow) * (long)K;
  float acc[8][8] = {};

  for (int k0 = 0; k0 < K; k0 += BK) {
#pragma unroll
    for (int i = 0; i < 2; i++) {
      const int q = lq + i;
      const float4 av = *(const float4*)(Aptr + k0 + q * 4);
      const float4 wv = *(const float4*)(Wptr + k0 + q * 4);
      As[q * 4 + 0][lrow] = av.x; As[q * 4 + 1][lrow] = av.y;
      As[q * 4 + 2][lrow] = av.z; As[q * 4 + 3][lrow] = av.w;
      Ws[q * 4 + 0][lrow] = wv.x; Ws[q * 4 + 1][lrow] = wv.y;
      Ws[q * 4 + 2][lrow] = wv.z; Ws[q * 4 + 3][lrow] = wv.w;
    }
    __syncthreads();
#pragma unroll
    for (int kk = 0; kk < BK; kk++) {
      const float4 a0 = *(const float4*)&As[kk][ty * 8];
      const float4 a1 = *(const float4*)&As[kk][ty * 8 + 4];
      const float4 b0 = *(const float4*)&Ws[kk][tx * 8];
      const float4 b1 = *(const float4*)&Ws[kk][tx * 8 + 4];
      const float a[8] = {a0.x, a0.y, a0.z, a0.w, a1.x, a1.y, a1.z, a1.w};
      const float b[8] = {b0.x, b0.y, b0.z, b0.w, b1.x, b1.y, b1.z, b1.w};
#pragma unroll
      for (int i = 0; i < 8; i++)
#pragma unroll
        for (int j = 0; j < 8; j++)
          acc[i][j] += a[i] * b[j];
    }
    __syncthreads();
  }

  const long crow = rowA + ty * 8;
  const int ccol = (int)colW + tx * 8;
  float bv[8];
#pragma unroll
  for (int j = 0; j < 8; j++) bv[j] = bias[ccol + j];
#pragma unroll
  for (int i = 0; i < 8; i++) {
    float o[8];
#pragma unroll
    for (int j = 0; j < 8; j++) {
      float v = acc[i][j] + bv[j];
      if (ACT) v = v > 0.f ? (v + 1.f) : __expf(v);  // elu(x)+1
      o[j] = v;
    }
    float* cp = C + (crow + i) * (long)N + ccol;
    *(float4*)cp = make_float4(o[0], o[1], o[2], o[3]);
    *(float4*)(cp + 4) = make_float4(o[4], o[5], o[6], o[7]);
  }
}

// kv[bh][d][m] = sum_n k[n][d]*v[n][m]; ksum[bh][d] = sum_n k[n][d].
// Block: one (b,h) x 1024-row chunk; 64x64 K/V tiles in LDS; thread owns
// (d = tid>>2, 16-wide m slice). AtomicAdd partials (8 blocks/head).
__global__ __launch_bounds__(256)
void kv_reduce_kernel(const float* __restrict__ kp, const float* __restrict__ vp,
                      float* __restrict__ kv, float* __restrict__ ksum) {
  const int bh = blockIdx.y;
  const int b = bh >> 4, h = bh & 15;
  const int n0 = blockIdx.x * CHUNK;
  __shared__ float Kt[64][64];
  __shared__ float Vt[64][64];
  const int tid = threadIdx.x;
  const int d = tid >> 2;
  const int mq = (tid & 3) * 16;
  float acc[16] = {};
  float ks = 0.f;
  const long base = (long)b * NSEQ * DM + h * DK;

  for (int nt = 0; nt < CHUNK; nt += 64) {
#pragma unroll
    for (int i = 0; i < 4; i++) {
      const int idx = tid + i * 256;
      const int r = idx >> 4, q = (idx & 15) * 4;
      const long g = base + (long)(n0 + nt + r) * DM + q;
      *(float4*)&Kt[r][q] = *(const float4*)(kp + g);
      *(float4*)&Vt[r][q] = *(const float4*)(vp + g);
    }
    __syncthreads();
#pragma unroll 4
    for (int r = 0; r < 64; r++) {
      const float kd = Kt[r][d];
      ks += kd;
#pragma unroll
      for (int j = 0; j < 16; j++) acc[j] += kd * Vt[r][mq + j];
    }
    __syncthreads();
  }
  if ((tid & 3) == 0) atomicAdd(&ksum[bh * DK + d], ks);
#pragma unroll
  for (int j = 0; j < 16; j++)
    atomicAdd(&kv[(bh * DK + d) * DK + mq + j], acc[j]);
}

// out[n][m] = (sum_d q[n][d]*kv[d][m]) / (sum_d q[n][d]*ksum[d] + eps)
// Block: one (b,h) x 64-row chunk. kv + Q tile in LDS; thread owns
// (row = tid>>2, 16-wide m slice).
__global__ __launch_bounds__(256)
void attn_apply_kernel(const float* __restrict__ qp, const float* __restrict__ kv,
                       const float* __restrict__ ksum, float* __restrict__ attn) {
  const int bh = blockIdx.y;
  const int b = bh >> 4, h = bh & 15;
  const int n0 = blockIdx.x * 64;
  __shared__ float KV[64][64];
  __shared__ float KS[64];
  __shared__ float Qt[64][64];
  const int tid = threadIdx.x;
  const long base = (long)b * NSEQ * DM + h * DK;

#pragma unroll
  for (int i = 0; i < 4; i++) {
    const int idx = tid + i * 256;
    *(float4*)&KV[0][idx * 4] = *(const float4*)(kv + (long)bh * DK * DK + idx * 4);
  }
  if (tid < 64) KS[tid] = ksum[bh * DK + tid];
#pragma unroll
  for (int i = 0; i < 4; i++) {
    const int idx = tid + i * 256;
    const int r = idx >> 4, q = (idx & 15) * 4;
    *(float4*)&Qt[r][q] = *(const float4*)(qp + base + (long)(n0 + r) * DM + q);
  }
  __syncthreads();

  const int r = tid >> 2;
  const int mq = (tid & 3) * 16;
  float acc[16] = {};
  float norm = EPS_F;
#pragma unroll 4
  for (int dd = 0; dd < 64; dd++) {
    const float qd = Qt[r][dd];
    norm += qd * KS[dd];
#pragma unroll
    for (int j = 0; j < 16; j++) acc[j] += qd * KV[dd][mq + j];
  }
  const float inv = 1.f / norm;
  float* op = attn + base + (long)(n0 + r) * DM + mq;
  *(float4*)(op + 0) = make_float4(acc[0] * inv, acc[1] * inv, acc[2] * inv, acc[3] * inv);
  *(float4*)(op + 4) = make_float4(acc[4] * inv, acc[5] * inv, acc[6] * inv, acc[7] * inv);
  *(float4*)(op + 8) = make_float4(acc[8] * inv, acc[9] * inv, acc[10] * inv, acc[11] * inv);
  *(float4*)(op + 12) = make_float4(acc[12] * inv, acc[13] * inv, acc[14] * inv, acc[15] * inv);
}

extern "C" void kernel_launch(void* const* d_in, const int* in_sizes, int n_in,
                              void* d_out, int out_size, void* d_ws, size_t ws_size,
                              hipStream_t stream) {
  const float* query = (const float*)d_in[0];
  const float* key   = (const float*)d_in[1];
  const float* value = (const float*)d_in[2];
  const float* wq = (const float*)d_in[3];
  const float* bq = (const float*)d_in[4];
  const float* wk = (const float*)d_in[5];
  const float* bk = (const float*)d_in[6];
  const float* wv = (const float*)d_in[7];
  const float* bv = (const float*)d_in[8];
  const float* wo = (const float*)d_in[9];
  const float* bo = (const float*)d_in[10];
  float* out = (float*)d_out;

  // Workspace layout (floats): qp | kp | vp | kv | ksum.  attn aliases kp
  // (kp is dead after kv_reduce).  Total ~202 MB.
  float* qp  = (float*)d_ws;
  float* kp  = qp + (size_t)MROWS * DM;
  float* vp  = kp + (size_t)MROWS * DM;
  float* kvw = vp + (size_t)MROWS * DM;
  float* ksw = kvw + (size_t)BSZ * NHEADS * DK * DK;
  float* attn = kp;

  // kv/ksum are accumulated via atomics -- zero them (ws is poisoned 0xAA).
  hipMemsetAsync(kvw, 0,
                 (size_t)(BSZ * NHEADS * DK * DK + BSZ * NHEADS * DK) * sizeof(float),
                 stream);

  const dim3 blk(256);
  const dim3 ggrid(DM / 128, MROWS / 128);
  gemm_bias_kernel<1><<<ggrid, blk, 0, stream>>>(query, wq, bq, qp);
  gemm_bias_kernel<1><<<ggrid, blk, 0, stream>>>(key,   wk, bk, kp);
  gemm_bias_kernel<0><<<ggrid, blk, 0, stream>>>(value, wv, bv, vp);
  kv_reduce_kernel<<<dim3(NSEQ / CHUNK, BSZ * NHEADS), blk, 0, stream>>>(kp, vp, kvw, ksw);
  attn_apply_kernel<<<dim3(NSEQ / 64, BSZ * NHEADS), blk, 0, stream>>>(qp, kvw, ksw, attn);
  gemm_bias_kernel<0><<<ggrid, blk, 0, stream>>>(attn, wo, bo, out);
}

// Round 2
// 922.301 us; speedup vs baseline: 2.2016x; 2.2016x over previous
//
#include <hip/hip_runtime.h>

#define DM 1024
#define NHEADS 16
#define DK 64
#define BSZ 2
#define NSEQ 8192
#define MROWS (BSZ*NSEQ)
#define CHUNK 1024

typedef unsigned short u16;
typedef __attribute__((ext_vector_type(8))) short short8;
typedef __attribute__((ext_vector_type(4))) float f32x4;

constexpr float EPS_F = 1e-6f;

__device__ __forceinline__ u16 f2bf(float x) {
  union { float f; unsigned u; } c; c.f = x;
  unsigned r = c.u + 0x7FFFu + ((c.u >> 16) & 1u);
  return (u16)(r >> 16);
}
__device__ __forceinline__ float bf2f(u16 h) {
  union { unsigned u; float f; } c; c.u = ((unsigned)h) << 16;
  return c.f;
}

typedef __attribute__((address_space(1))) const void gvoid_t;
typedef __attribute__((address_space(3))) void lvoid_t;
__device__ __forceinline__ void gl2lds16(const void* g, void* l) {
  // width=16: global_load_lds_dwordx4; LDS dst = wave-uniform base + lane*16
  __builtin_amdgcn_global_load_lds((gvoid_t*)g, (lvoid_t*)l, 16, 0, 0);
}

// fp32 -> (hi bf16, lo bf16) split.  hi = rne(x), lo = rne(x - hi).
__global__ __launch_bounds__(256)
void split_kernel(const float* __restrict__ src, u16* __restrict__ hi,
                  u16* __restrict__ lo, int n4) {
  int i = blockIdx.x * 256 + threadIdx.x;
  const int stride = gridDim.x * 256;
  for (; i < n4; i += stride) {
    const float4 v = ((const float4*)src)[i];
    const u16 h0 = f2bf(v.x), h1 = f2bf(v.y), h2 = f2bf(v.z), h3 = f2bf(v.w);
    const u16 l0 = f2bf(v.x - bf2f(h0)), l1 = f2bf(v.y - bf2f(h1));
    const u16 l2 = f2bf(v.z - bf2f(h2)), l3 = f2bf(v.w - bf2f(h3));
    ((ushort4*)hi)[i] = make_ushort4(h0, h1, h2, h3);
    ((ushort4*)lo)[i] = make_ushort4(l0, l1, l2, l3);
  }
}

// C[M x N] = (Ahi+Alo)[M x K] @ (Whi+Wlo)[N x K]^T + bias, via 3 bf16 MFMA
// passes (hi*hi + hi*lo + lo*hi).  128x128 tile, BK=32, 4 waves in 2x2, each
// wave 64x64 = 4x4 tiles of 16x16x32 MFMA.  global_load_lds width-16 staging.
template<int ACT, int OUT_BF16>
__global__ __launch_bounds__(256)
void gemm_mfma_kernel(const u16* __restrict__ Ahi, const u16* __restrict__ Alo,
                      const u16* __restrict__ Whi, const u16* __restrict__ Wlo,
                      const float* __restrict__ bias, void* __restrict__ Cout) {
  constexpr int K = DM, N = DM, BK = 32;
  __shared__ u16 Ash[128 * BK], Asl[128 * BK], Wsh[128 * BK], Wsl[128 * BK];
  const int tid = threadIdx.x;
  const int lane = tid & 63, wv = tid >> 6;
  const int bRow = blockIdx.y * 128, bCol = blockIdx.x * 128;

  // staging: slot s in [0,512) covers tile row s>>2, k-offset (s&3)*8.
  // one global_load_lds call: wave writes a contiguous 1 KB LDS region.
  const int s0 = wv * 128 + lane;
  const int s1 = s0 + 64;
  const int r0 = s0 >> 2, c0 = (s0 & 3) * 8;
  const int r1 = s1 >> 2, c1 = (s1 & 3) * 8;
  const u16* gAh0 = Ahi + (size_t)(bRow + r0) * K + c0;
  const u16* gAh1 = Ahi + (size_t)(bRow + r1) * K + c1;
  const u16* gAl0 = Alo + (size_t)(bRow + r0) * K + c0;
  const u16* gAl1 = Alo + (size_t)(bRow + r1) * K + c1;
  const u16* gWh0 = Whi + (size_t)(bCol + r0) * K + c0;
  const u16* gWh1 = Whi + (size_t)(bCol + r1) * K + c1;
  const u16* gWl0 = Wlo + (size_t)(bCol + r0) * K + c0;
  const u16* gWl1 = Wlo + (size_t)(bCol + r1) * K + c1;
  u16* const lA0 = Ash + (wv * 2 + 0) * 512;
  u16* const lA1 = Ash + (wv * 2 + 1) * 512;
  u16* const lB0 = Asl + (wv * 2 + 0) * 512;
  u16* const lB1 = Asl + (wv * 2 + 1) * 512;
  u16* const lC0 = Wsh + (wv * 2 + 0) * 512;
  u16* const lC1 = Wsh + (wv * 2 + 1) * 512;
  u16* const lD0 = Wsl + (wv * 2 + 0) * 512;
  u16* const lD1 = Wsl + (wv * 2 + 1) * 512;

  const int wm = (wv & 1) * 64, wn = (wv >> 1) * 64;
  const int fr = lane & 15, fk = (lane >> 4) * 8;

  f32x4 acc[4][4] = {};

  for (int k0 = 0; k0 < K; k0 += BK) {
    gl2lds16(gAh0 + k0, lA0); gl2lds16(gAh1 + k0, lA1);
    gl2lds16(gAl0 + k0, lB0); gl2lds16(gAl1 + k0, lB1);
    gl2lds16(gWh0 + k0, lC0); gl2lds16(gWh1 + k0, lC1);
    gl2lds16(gWl0 + k0, lD0); gl2lds16(gWl1 + k0, lD1);
    __syncthreads();

    short8 ah[4], al[4], bh[4], bl[4];
#pragma unroll
    for (int mt = 0; mt < 4; mt++) {
      ah[mt] = *(const short8*)(Ash + (wm + mt * 16 + fr) * BK + fk);
      al[mt] = *(const short8*)(Asl + (wm + mt * 16 + fr) * BK + fk);
    }
#pragma unroll
    for (int nt = 0; nt < 4; nt++) {
      bh[nt] = *(const short8*)(Wsh + (wn + nt * 16 + fr) * BK + fk);
      bl[nt] = *(const short8*)(Wsl + (wn + nt * 16 + fr) * BK + fk);
    }
#pragma unroll
    for (int mt = 0; mt < 4; mt++)
#pragma unroll
      for (int nt = 0; nt < 4; nt++) {
        acc[mt][nt] = __builtin_amdgcn_mfma_f32_16x16x32_bf16(ah[mt], bh[nt], acc[mt][nt], 0, 0, 0);
        acc[mt][nt] = __builtin_amdgcn_mfma_f32_16x16x32_bf16(ah[mt], bl[nt], acc[mt][nt], 0, 0, 0);
        acc[mt][nt] = __builtin_amdgcn_mfma_f32_16x16x32_bf16(al[mt], bh[nt], acc[mt][nt], 0, 0, 0);
      }
    __syncthreads();
  }

  // epilogue: C/D layout col = lane&15, row = (lane>>4)*4 + reg  [m89]
  const int erow = (lane >> 4) * 4;
  const int ecol = lane & 15;
  float bv[4];
#pragma unroll
  for (int nt = 0; nt < 4; nt++) bv[nt] = bias[bCol + wn + nt * 16 + ecol];
#pragma unroll
  for (int mt = 0; mt < 4; mt++)
#pragma unroll
    for (int nt = 0; nt < 4; nt++)
#pragma unroll
      for (int r = 0; r < 4; r++) {
        const size_t row = (size_t)bRow + wm + mt * 16 + erow + r;
        const size_t col = (size_t)bCol + wn + nt * 16 + ecol;
        float v = acc[mt][nt][r] + bv[nt];
        if (ACT) v = v > 0.f ? (v + 1.f) : __expf(v);  // elu(x)+1
        if (OUT_BF16) ((u16*)Cout)[row * N + col] = f2bf(v);
        else          ((float*)Cout)[row * N + col] = v;
      }
}

// kv[bh][d][m] = sum_n k[n][d]*v[n][m]; ksum[bh][d] = sum_n k[n][d].  bf16 in.
__global__ __launch_bounds__(256)
void kv_reduce_kernel(const u16* __restrict__ kp, const u16* __restrict__ vp,
                      float* __restrict__ kv, float* __restrict__ ksum) {
  const int bh = blockIdx.y;
  const int b = bh >> 4, h = bh & 15;
  const int n0 = blockIdx.x * CHUNK;
  __shared__ float Kt[64][64];
  __shared__ float Vt[64][64];
  const int tid = threadIdx.x;
  const int d = tid >> 2;
  const int mq = (tid & 3) * 16;
  float acc[16] = {};
  float ks = 0.f;
  const size_t base = (size_t)b * NSEQ * DM + h * DK;

  for (int nt = 0; nt < CHUNK; nt += 64) {
#pragma unroll
    for (int i = 0; i < 2; i++) {
      const int idx = tid + i * 256;       // 0..511
      const int r = idx >> 3, c = (idx & 7) * 8;
      const size_t g = base + (size_t)(n0 + nt + r) * DM + c;
      const short8 k8 = *(const short8*)(kp + g);
      const short8 v8 = *(const short8*)(vp + g);
#pragma unroll
      for (int j = 0; j < 8; j++) {
        Kt[r][c + j] = bf2f((u16)k8[j]);
        Vt[r][c + j] = bf2f((u16)v8[j]);
      }
    }
    __syncthreads();
#pragma unroll 4
    for (int r = 0; r < 64; r++) {
      const float kd = Kt[r][d];
      ks += kd;
#pragma unroll
      for (int j = 0; j < 16; j++) acc[j] += kd * Vt[r][mq + j];
    }
    __syncthreads();
  }
  if ((tid & 3) == 0) atomicAdd(&ksum[bh * DK + d], ks);
#pragma unroll
  for (int j = 0; j < 16; j++)
    atomicAdd(&kv[(bh * DK + d) * DK + mq + j], acc[j]);
}

// out = (q @ kv) / (q . ksum + eps); writes hi/lo bf16 split for final GEMM.
__global__ __launch_bounds__(256)
void attn_apply_kernel(const u16* __restrict__ qp, const float* __restrict__ kv,
                       const float* __restrict__ ksum,
                       u16* __restrict__ ahi, u16* __restrict__ alo) {
  const int bh = blockIdx.y;
  const int b = bh >> 4, h = bh & 15;
  const int n0 = blockIdx.x * 64;
  __shared__ float KV[64][64];
  __shared__ float KS[64];
  __shared__ float Qt[64][64];
  const int tid = threadIdx.x;
  const size_t base = (size_t)b * NSEQ * DM + h * DK;

#pragma unroll
  for (int i = 0; i < 4; i++) {
    const int idx = tid + i * 256;
    *(float4*)&KV[0][idx * 4] = ((const float4*)(kv + (size_t)bh * DK * DK))[idx];
  }
  if (tid < 64) KS[tid] = ksum[bh * DK + tid];
#pragma unroll
  for (int i = 0; i < 2; i++) {
    const int idx = tid + i * 256;
    const int r = idx >> 3, c = (idx & 7) * 8;
    const short8 q8 = *(const short8*)(qp + base + (size_t)(n0 + r) * DM + c);
#pragma unroll
    for (int j = 0; j < 8; j++) Qt[r][c + j] = bf2f((u16)q8[j]);
  }
  __syncthreads();

  const int r = tid >> 2;
  const int mq = (tid & 3) * 16;
  float acc[16] = {};
  float norm = EPS_F;
#pragma unroll 4
  for (int dd = 0; dd < 64; dd++) {
    const float qd = Qt[r][dd];
    norm += qd * KS[dd];
#pragma unroll
    for (int j = 0; j < 16; j++) acc[j] += qd * KV[dd][mq + j];
  }
  const float inv = 1.f / norm;
  short8 h8[2], l8[2];
#pragma unroll
  for (int j = 0; j < 16; j++) {
    const float v = acc[j] * inv;
    const u16 hh = f2bf(v);
    h8[j >> 3][j & 7] = (short)hh;
    l8[j >> 3][j & 7] = (short)f2bf(v - bf2f(hh));
  }
  const size_t o = base + (size_t)(n0 + r) * DM + mq;
  *(short8*)(ahi + o) = h8[0];
  *(short8*)(ahi + o + 8) = h8[1];
  *(short8*)(alo + o) = l8[0];
  *(short8*)(alo + o + 8) = l8[1];
}

extern "C" void kernel_launch(void* const* d_in, const int* in_sizes, int n_in,
                              void* d_out, int out_size, void* d_ws, size_t ws_size,
                              hipStream_t stream) {
  const float* query = (const float*)d_in[0];
  const float* key   = (const float*)d_in[1];
  const float* value = (const float*)d_in[2];
  const float* wq = (const float*)d_in[3];
  const float* bq = (const float*)d_in[4];
  const float* wk = (const float*)d_in[5];
  const float* bk = (const float*)d_in[6];
  const float* wv = (const float*)d_in[7];
  const float* bv = (const float*)d_in[8];
  const float* wo = (const float*)d_in[9];
  const float* bo = (const float*)d_in[10];
  float* out = (float*)d_out;

  constexpr size_t WELEM = (size_t)DM * DM;          // 1M
  constexpr size_t AELEM = (size_t)MROWS * DM;       // 16.7M

  // ws layout (u16 unless noted): 8 weight hi/lo (16 MB) | chi/clo (67 MB,
  // also reused as attn hi/lo) | qp/kp/vp bf16 (100 MB) | kv/ksum f32.
  char* p = (char*)d_ws;
  auto take = [&](size_t bytes) { char* q = p; p += (bytes + 255) & ~(size_t)255; return q; };
  u16* wqh = (u16*)take(WELEM * 2); u16* wql = (u16*)take(WELEM * 2);
  u16* wkh = (u16*)take(WELEM * 2); u16* wkl = (u16*)take(WELEM * 2);
  u16* wvh = (u16*)take(WELEM * 2); u16* wvl = (u16*)take(WELEM * 2);
  u16* woh = (u16*)take(WELEM * 2); u16* wol = (u16*)take(WELEM * 2);
  u16* chi = (u16*)take(AELEM * 2); u16* clo = (u16*)take(AELEM * 2);
  u16* qp  = (u16*)take(AELEM * 2);
  u16* kp  = (u16*)take(AELEM * 2);
  u16* vp  = (u16*)take(AELEM * 2);
  float* kvw = (float*)take((size_t)BSZ * NHEADS * DK * DK * 4);
  float* ksw = (float*)take((size_t)BSZ * NHEADS * DK * 4);
  u16* ahi = chi; u16* alo = clo;   // chi/clo dead after gemmV reads them

  hipMemsetAsync(kvw, 0,
                 (size_t)(BSZ * NHEADS * DK * DK + BSZ * NHEADS * DK) * sizeof(float),
                 stream);

  const dim3 blk(256);
  split_kernel<<<256, blk, 0, stream>>>(wq, wqh, wql, (int)(WELEM / 4));
  split_kernel<<<256, blk, 0, stream>>>(wk, wkh, wkl, (int)(WELEM / 4));
  split_kernel<<<256, blk, 0, stream>>>(wv, wvh, wvl, (int)(WELEM / 4));
  split_kernel<<<256, blk, 0, stream>>>(wo, woh, wol, (int)(WELEM / 4));

  const dim3 ggrid(DM / 128, MROWS / 128);
  split_kernel<<<2048, blk, 0, stream>>>(query, chi, clo, (int)(AELEM / 4));
  gemm_mfma_kernel<1, 1><<<ggrid, blk, 0, stream>>>(chi, clo, wqh, wql, bq, qp);
  split_kernel<<<2048, blk, 0, stream>>>(key, chi, clo, (int)(AELEM / 4));
  gemm_mfma_kernel<1, 1><<<ggrid, blk, 0, stream>>>(chi, clo, wkh, wkl, bk, kp);
  split_kernel<<<2048, blk, 0, stream>>>(value, chi, clo, (int)(AELEM / 4));
  gemm_mfma_kernel<0, 1><<<ggrid, blk, 0, stream>>>(chi, clo, wvh, wvl, bv, vp);

  kv_reduce_kernel<<<dim3(NSEQ / CHUNK, BSZ * NHEADS), blk, 0, stream>>>(kp, vp, kvw, ksw);
  attn_apply_kernel<<<dim3(NSEQ / 64, BSZ * NHEADS), blk, 0, stream>>>(qp, kvw, ksw, ahi, alo);
  gemm_mfma_kernel<0, 0><<<ggrid, blk, 0, stream>>>(ahi, alo, woh, wol, bo, out);
}

// Round 3
// 778.811 us; speedup vs baseline: 2.6073x; 1.1842x over previous
//
#include <hip/hip_runtime.h>

#define DM 1024
#define NHEADS 16
#define DK 64
#define BSZ 2
#define NSEQ 8192
#define MROWS (BSZ*NSEQ)
#define NCHUNKS 16
#define CHUNKN 512

typedef unsigned short u16;
typedef __attribute__((ext_vector_type(8))) short short8;
typedef __attribute__((ext_vector_type(4))) float f32x4;

constexpr float EPS_F = 1e-6f;

__device__ __forceinline__ u16 f2bf(float x) {
  union { float f; unsigned u; } c; c.f = x;
  unsigned r = c.u + 0x7FFFu + ((c.u >> 16) & 1u);
  return (u16)(r >> 16);
}
__device__ __forceinline__ float bf2f(u16 h) {
  union { unsigned u; float f; } c; c.u = ((unsigned)h) << 16;
  return c.f;
}

typedef __attribute__((address_space(1))) const void gvoid_t;
typedef __attribute__((address_space(3))) void lvoid_t;
__device__ __forceinline__ void gl2lds16(const void* g, void* l) {
  // width=16: global_load_lds_dwordx4; LDS dst = wave-uniform base + lane*16
  __builtin_amdgcn_global_load_lds((gvoid_t*)g, (lvoid_t*)l, 16, 0, 0);
}

// fp32 -> (hi bf16, lo bf16) split.  hi = rne(x), lo = rne(x - hi).
__global__ __launch_bounds__(256)
void split_kernel(const float* __restrict__ src, u16* __restrict__ hi,
                  u16* __restrict__ lo, int n4) {
  int i = blockIdx.x * 256 + threadIdx.x;
  const int stride = gridDim.x * 256;
  for (; i < n4; i += stride) {
    const float4 v = ((const float4*)src)[i];
    const u16 h0 = f2bf(v.x), h1 = f2bf(v.y), h2 = f2bf(v.z), h3 = f2bf(v.w);
    const u16 l0 = f2bf(v.x - bf2f(h0)), l1 = f2bf(v.y - bf2f(h1));
    const u16 l2 = f2bf(v.z - bf2f(h2)), l3 = f2bf(v.w - bf2f(h3));
    ((ushort4*)hi)[i] = make_ushort4(h0, h1, h2, h3);
    ((ushort4*)lo)[i] = make_ushort4(l0, l1, l2, l3);
  }
}

// C[M x N] = (Ahi+Alo)[M x K] @ (Whi+Wlo)[N x K]^T + bias, via 3 bf16 MFMA
// passes (hi*hi + hi*lo + lo*hi).  128x128 tile, BK=32, 4 waves 2x2, each
// wave 64x64 = 4x4 tiles of 16x16x32 MFMA.  global_load_lds width-16 staging.
// MODE: 0 = f32 normal, 1 = bf16 normal, 2 = bf16 transposed (C^T[N][M]),
//       3 = bf16 transposed + ksum column-sum atomics (for K projection).
template<int ACT, int MODE>
__global__ __launch_bounds__(256)
void gemm_mfma_kernel(const u16* __restrict__ Ahi, const u16* __restrict__ Alo,
                      const u16* __restrict__ Whi, const u16* __restrict__ Wlo,
                      const float* __restrict__ bias, void* __restrict__ Cout,
                      float* __restrict__ ksum) {
  constexpr int K = DM, N = DM, BK = 32;
  __shared__ u16 Ash[128 * BK], Asl[128 * BK], Wsh[128 * BK], Wsl[128 * BK];
  const int tid = threadIdx.x;
  const int lane = tid & 63, wv = tid >> 6;
  const int bRow = blockIdx.y * 128, bCol = blockIdx.x * 128;

  const int s0 = wv * 128 + lane;
  const int s1 = s0 + 64;
  const int r0 = s0 >> 2, c0 = (s0 & 3) * 8;
  const int r1 = s1 >> 2, c1 = (s1 & 3) * 8;
  const u16* gAh0 = Ahi + (size_t)(bRow + r0) * K + c0;
  const u16* gAh1 = Ahi + (size_t)(bRow + r1) * K + c1;
  const u16* gAl0 = Alo + (size_t)(bRow + r0) * K + c0;
  const u16* gAl1 = Alo + (size_t)(bRow + r1) * K + c1;
  const u16* gWh0 = Whi + (size_t)(bCol + r0) * K + c0;
  const u16* gWh1 = Whi + (size_t)(bCol + r1) * K + c1;
  const u16* gWl0 = Wlo + (size_t)(bCol + r0) * K + c0;
  const u16* gWl1 = Wlo + (size_t)(bCol + r1) * K + c1;
  u16* const lA0 = Ash + (wv * 2 + 0) * 512;
  u16* const lA1 = Ash + (wv * 2 + 1) * 512;
  u16* const lB0 = Asl + (wv * 2 + 0) * 512;
  u16* const lB1 = Asl + (wv * 2 + 1) * 512;
  u16* const lC0 = Wsh + (wv * 2 + 0) * 512;
  u16* const lC1 = Wsh + (wv * 2 + 1) * 512;
  u16* const lD0 = Wsl + (wv * 2 + 0) * 512;
  u16* const lD1 = Wsl + (wv * 2 + 1) * 512;

  const int wm = (wv & 1) * 64, wn = (wv >> 1) * 64;
  const int fr = lane & 15, fk = (lane >> 4) * 8;

  f32x4 acc[4][4] = {};

  for (int k0 = 0; k0 < K; k0 += BK) {
    gl2lds16(gAh0 + k0, lA0); gl2lds16(gAh1 + k0, lA1);
    gl2lds16(gAl0 + k0, lB0); gl2lds16(gAl1 + k0, lB1);
    gl2lds16(gWh0 + k0, lC0); gl2lds16(gWh1 + k0, lC1);
    gl2lds16(gWl0 + k0, lD0); gl2lds16(gWl1 + k0, lD1);
    __syncthreads();

    short8 ah[4], al[4], bh[4], bl[4];
#pragma unroll
    for (int mt = 0; mt < 4; mt++) {
      ah[mt] = *(const short8*)(Ash + (wm + mt * 16 + fr) * BK + fk);
      al[mt] = *(const short8*)(Asl + (wm + mt * 16 + fr) * BK + fk);
    }
#pragma unroll
    for (int nt = 0; nt < 4; nt++) {
      bh[nt] = *(const short8*)(Wsh + (wn + nt * 16 + fr) * BK + fk);
      bl[nt] = *(const short8*)(Wsl + (wn + nt * 16 + fr) * BK + fk);
    }
#pragma unroll
    for (int mt = 0; mt < 4; mt++)
#pragma unroll
      for (int nt = 0; nt < 4; nt++) {
        acc[mt][nt] = __builtin_amdgcn_mfma_f32_16x16x32_bf16(ah[mt], bh[nt], acc[mt][nt], 0, 0, 0);
        acc[mt][nt] = __builtin_amdgcn_mfma_f32_16x16x32_bf16(ah[mt], bl[nt], acc[mt][nt], 0, 0, 0);
        acc[mt][nt] = __builtin_amdgcn_mfma_f32_16x16x32_bf16(al[mt], bh[nt], acc[mt][nt], 0, 0, 0);
      }
    __syncthreads();
  }

  // epilogue: C/D layout col = lane&15, row = (lane>>4)*4 + reg  [m89]
  const int erow = (lane >> 4) * 4;
  const int ecol = lane & 15;
  float bv[4];
#pragma unroll
  for (int nt = 0; nt < 4; nt++) bv[nt] = bias[bCol + wn + nt * 16 + ecol];
  float csum[4] = {0.f, 0.f, 0.f, 0.f};
#pragma unroll
  for (int mt = 0; mt < 4; mt++)
#pragma unroll
    for (int nt = 0; nt < 4; nt++)
#pragma unroll
      for (int r = 0; r < 4; r++) {
        const size_t row = (size_t)bRow + wm + mt * 16 + erow + r;
        const size_t col = (size_t)bCol + wn + nt * 16 + ecol;
        float v = acc[mt][nt][r] + bv[nt];
        if (ACT) v = v > 0.f ? (v + 1.f) : __expf(v);  // elu(x)+1
        if (MODE == 0)      ((float*)Cout)[row * N + col] = v;
        else if (MODE == 1) ((u16*)Cout)[row * N + col] = f2bf(v);
        else {
          ((u16*)Cout)[col * (size_t)MROWS + row] = f2bf(v);  // C^T
          if (MODE == 3) csum[nt] += v;
        }
      }
  if (MODE == 3) {
    const int bidx = bRow >> 13;  // which batch this 128-row strip is in
#pragma unroll
    for (int nt = 0; nt < 4; nt++) {
      float s = csum[nt];
      s += __shfl_xor(s, 16, 64);
      s += __shfl_xor(s, 32, 64);   // all quads now hold the 64-row column sum
      if ((lane >> 4) == 0)
        atomicAdd(&ksum[bidx * DM + bCol + wn + nt * 16 + ecol], s);
    }
  }
}

// KVT[m][d] partial = sum_n vT[m][n]*kT[d][n] over this block's 512-n chunk.
// Pure MFMA: stage 64x64 kT/vT tiles (row-major, n-contiguous) via
// global_load_lds; 4 waves 2x2 over (m,d), each 32x32.  Deterministic f32
// partials to global (reduced by kvt_reduce_kernel).
__global__ __launch_bounds__(256)
void kv_mfma_kernel(const u16* __restrict__ kT, const u16* __restrict__ vT,
                    float* __restrict__ part) {
  const int bh = blockIdx.y;
  const int b = bh >> 4, h = bh & 15;
  const size_t colbase = (size_t)b * NSEQ + blockIdx.x * CHUNKN;
  __shared__ u16 kts[64 * 64], vts[64 * 64];
  const int tid = threadIdx.x, lane = tid & 63, w = tid >> 6;
  const int wm = (w & 1) * 32, wd = (w >> 1) * 32;
  const int fr = lane & 15, fk = (lane >> 4) * 8;
  const int srow = lane >> 3, scol = (lane & 7) * 8;

  f32x4 acc[2][2] = {};

  for (int s = 0; s < CHUNKN / 64; s++) {
    const size_t cb = colbase + s * 64 + scol;
#pragma unroll
    for (int i = 0; i < 2; i++) {
      const int ii = w * 2 + i;                    // instr 0..7, rows ii*8..+8
      const size_t grow = (size_t)(h * DK + ii * 8 + srow) * MROWS + cb;
      gl2lds16(vT + grow, vts + ii * 512);
      gl2lds16(kT + grow, kts + ii * 512);
    }
    __syncthreads();
#pragma unroll
    for (int ks = 0; ks < 2; ks++) {
      short8 af[2], bfr[2];
#pragma unroll
      for (int mt = 0; mt < 2; mt++)
        af[mt] = *(const short8*)(vts + (wm + mt * 16 + fr) * 64 + ks * 32 + fk);
#pragma unroll
      for (int dt = 0; dt < 2; dt++)
        bfr[dt] = *(const short8*)(kts + (wd + dt * 16 + fr) * 64 + ks * 32 + fk);
#pragma unroll
      for (int mt = 0; mt < 2; mt++)
#pragma unroll
        for (int dt = 0; dt < 2; dt++)
          acc[mt][dt] = __builtin_amdgcn_mfma_f32_16x16x32_bf16(af[mt], bfr[dt], acc[mt][dt], 0, 0, 0);
    }
    __syncthreads();
  }

  float* pp = part + ((size_t)blockIdx.x * 32 + bh) * (DK * DK);
  const int erow = (lane >> 4) * 4, ecol = lane & 15;
#pragma unroll
  for (int mt = 0; mt < 2; mt++)
#pragma unroll
    for (int dt = 0; dt < 2; dt++)
#pragma unroll
      for (int r = 0; r < 4; r++)
        pp[(wm + mt * 16 + erow + r) * DK + wd + dt * 16 + ecol] = acc[mt][dt][r];
}

// Reduce the 16 chunk-partials -> bf16 KVT[bh][m][d].
__global__ __launch_bounds__(256)
void kvt_reduce_kernel(const float* __restrict__ part, u16* __restrict__ kvt) {
  const int bh = blockIdx.x, t = threadIdx.x;
  const int i0 = t * 16;
  f32x4 s[4] = {};
  for (int c = 0; c < NCHUNKS; c++) {
    const f32x4* p = (const f32x4*)(part + ((size_t)c * 32 + bh) * (DK * DK) + i0);
#pragma unroll
    for (int q = 0; q < 4; q++) s[q] += p[q];
  }
  short8 o[2];
#pragma unroll
  for (int j = 0; j < 16; j++) o[j >> 3][j & 7] = (short)f2bf(s[j >> 2][j & 3]);
  *(short8*)(kvt + (size_t)bh * (DK * DK) + i0) = o[0];
  *(short8*)(kvt + (size_t)bh * (DK * DK) + i0 + 8) = o[1];
}

// out[n][m] = (q[n][:] . KVT[m][:]) / (q[n][:] . ksum + eps), per (b,h).
// Thin MFMA GEMM: K=64 (2 ksteps), block = 128 n x 64 m, B-frags in regs,
// A-frags straight from global (d-contiguous).  Writes hi/lo bf16 split.
__global__ __launch_bounds__(256)
void attn_mfma_kernel(const u16* __restrict__ qp, const u16* __restrict__ kvt,
                      const float* __restrict__ ksum,
                      u16* __restrict__ ahi, u16* __restrict__ alo) {
  const int bh = blockIdx.y;
  const int b = bh >> 4, h = bh & 15;
  const int n0 = blockIdx.x * 128;
  const int tid = threadIdx.x, lane = tid & 63, w = tid >> 6;
  const int fr = lane & 15, fk = (lane >> 4) * 8;
  __shared__ float norm_lds[128];

  short8 bfr[4][2];
#pragma unroll
  for (int mt = 0; mt < 4; mt++)
#pragma unroll
    for (int ks = 0; ks < 2; ks++)
      bfr[mt][ks] = *(const short8*)(kvt + (size_t)bh * (DK * DK) + (mt * 16 + fr) * DK + ks * 32 + fk);

  float ksf[2][8];
#pragma unroll
  for (int ks = 0; ks < 2; ks++)
#pragma unroll
    for (int j = 0; j < 8; j++)
      ksf[ks][j] = ksum[b * DM + h * DK + ks * 32 + fk + j];

  const int nb = n0 + w * 32;
  short8 af[2][2];
#pragma unroll
  for (int nt = 0; nt < 2; nt++)
#pragma unroll
    for (int ks = 0; ks < 2; ks++)
      af[nt][ks] = *(const short8*)(qp + (size_t)(b * NSEQ + nb + nt * 16 + fr) * DM + h * DK + ks * 32 + fk);

  f32x4 acc[2][4] = {};
#pragma unroll
  for (int nt = 0; nt < 2; nt++)
#pragma unroll
    for (int mt = 0; mt < 4; mt++)
#pragma unroll
      for (int ks = 0; ks < 2; ks++)
        acc[nt][mt] = __builtin_amdgcn_mfma_f32_16x16x32_bf16(af[nt][ks], bfr[mt][ks], acc[nt][mt], 0, 0, 0);

#pragma unroll
  for (int nt = 0; nt < 2; nt++) {
    float p = 0.f;
#pragma unroll
    for (int ks = 0; ks < 2; ks++)
#pragma unroll
      for (int j = 0; j < 8; j++)
        p += bf2f((u16)af[nt][ks][j]) * ksf[ks][j];
    p += __shfl_xor(p, 16, 64);
    p += __shfl_xor(p, 32, 64);
    if ((lane >> 4) == 0) norm_lds[w * 32 + nt * 16 + fr] = p + EPS_F;
  }
  __syncthreads();

  const int erow = (lane >> 4) * 4, ec = lane & 15;
#pragma unroll
  for (int nt = 0; nt < 2; nt++) {
    float inv[4];
#pragma unroll
    for (int r = 0; r < 4; r++) inv[r] = 1.f / norm_lds[w * 32 + nt * 16 + erow + r];
#pragma unroll
    for (int mt = 0; mt < 4; mt++)
#pragma unroll
      for (int r = 0; r < 4; r++) {
        const float v = acc[nt][mt][r] * inv[r];
        const size_t o = (size_t)(b * NSEQ + nb + nt * 16 + erow + r) * DM + h * DK + mt * 16 + ec;
        const u16 hh = f2bf(v);
        ahi[o] = hh;
        alo[o] = f2bf(v - bf2f(hh));
      }
  }
}

extern "C" void kernel_launch(void* const* d_in, const int* in_sizes, int n_in,
                              void* d_out, int out_size, void* d_ws, size_t ws_size,
                              hipStream_t stream) {
  const float* query = (const float*)d_in[0];
  const float* key   = (const float*)d_in[1];
  const float* value = (const float*)d_in[2];
  const float* wq = (const float*)d_in[3];
  const float* bq = (const float*)d_in[4];
  const float* wk = (const float*)d_in[5];
  const float* bk = (const float*)d_in[6];
  const float* wv = (const float*)d_in[7];
  const float* bv = (const float*)d_in[8];
  const float* wo = (const float*)d_in[9];
  const float* bo = (const float*)d_in[10];
  float* out = (float*)d_out;

  constexpr size_t WELEM = (size_t)DM * DM;
  constexpr size_t AELEM = (size_t)MROWS * DM;

  char* p = (char*)d_ws;
  auto take = [&](size_t bytes) { char* q = p; p += (bytes + 255) & ~(size_t)255; return q; };
  u16* wqh = (u16*)take(WELEM * 2); u16* wql = (u16*)take(WELEM * 2);
  u16* wkh = (u16*)take(WELEM * 2); u16* wkl = (u16*)take(WELEM * 2);
  u16* wvh = (u16*)take(WELEM * 2); u16* wvl = (u16*)take(WELEM * 2);
  u16* woh = (u16*)take(WELEM * 2); u16* wol = (u16*)take(WELEM * 2);
  u16* chi = (u16*)take(AELEM * 2); u16* clo = (u16*)take(AELEM * 2);
  u16* qp  = (u16*)take(AELEM * 2);
  u16* kT  = (u16*)take(AELEM * 2);
  u16* vT  = (u16*)take(AELEM * 2);
  float* part = (float*)take((size_t)NCHUNKS * 32 * DK * DK * 4);
  float* ksum = (float*)take((size_t)BSZ * DM * 4);
  u16* kvt = (u16*)take((size_t)BSZ * NHEADS * DK * DK * 2);
  u16* ahi = chi; u16* alo = clo;   // chi/clo dead after V-GEMM reads them

  // ksum accumulated via atomics in the K-GEMM epilogue -- zero it.
  hipMemsetAsync(ksum, 0, (size_t)BSZ * DM * 4, stream);

  const dim3 blk(256);
  split_kernel<<<256, blk, 0, stream>>>(wq, wqh, wql, (int)(WELEM / 4));
  split_kernel<<<256, blk, 0, stream>>>(wk, wkh, wkl, (int)(WELEM / 4));
  split_kernel<<<256, blk, 0, stream>>>(wv, wvh, wvl, (int)(WELEM / 4));
  split_kernel<<<256, blk, 0, stream>>>(wo, woh, wol, (int)(WELEM / 4));

  const dim3 ggrid(DM / 128, MROWS / 128);
  split_kernel<<<2048, blk, 0, stream>>>(query, chi, clo, (int)(AELEM / 4));
  gemm_mfma_kernel<1, 1><<<ggrid, blk, 0, stream>>>(chi, clo, wqh, wql, bq, qp, nullptr);
  split_kernel<<<2048, blk, 0, stream>>>(key, chi, clo, (int)(AELEM / 4));
  gemm_mfma_kernel<1, 3><<<ggrid, blk, 0, stream>>>(chi, clo, wkh, wkl, bk, kT, ksum);
  split_kernel<<<2048, blk, 0, stream>>>(value, chi, clo, (int)(AELEM / 4));
  gemm_mfma_kernel<0, 2><<<ggrid, blk, 0, stream>>>(chi, clo, wvh, wvl, bv, vT, nullptr);

  kv_mfma_kernel<<<dim3(NCHUNKS, BSZ * NHEADS), blk, 0, stream>>>(kT, vT, part);
  kvt_reduce_kernel<<<32, blk, 0, stream>>>(part, kvt);
  attn_mfma_kernel<<<dim3(NSEQ / 128, BSZ * NHEADS), blk, 0, stream>>>(qp, kvt, ksum, ahi, alo);
  gemm_mfma_kernel<0, 0><<<ggrid, blk, 0, stream>>>(ahi, alo, woh, wol, bo, out, nullptr);
}